// Round 4
// baseline (401.189 us; speedup 1.0000x reference)
//
#include <hip/hip_runtime.h>
#include <math.h>

#define NPG 1000
#define KTOP 500
#define C 64
#define EPG 16000   // edges per graph = NPG * DEG
#define BPG 63      // gather blocks per graph: ceil(250/4), 4 bases/block, 4 nodes/base-wave

__device__ __forceinline__ float readlane_f(float v, int l) {
    return __uint_as_float(__builtin_amdgcn_readlane(__float_as_uint(v), (unsigned)l));
}
__device__ __forceinline__ int readlane_i(int v, int l) {
    return (int)__builtin_amdgcn_readlane((unsigned)v, (unsigned)l);
}

// ---------------- fused per-graph CSR build: count + scan + scatter in LDS ----------------
__global__ __launch_bounds__(1024) void build_graph_k(const int* __restrict__ ei, int E,
                                                      int* __restrict__ deg,
                                                      float* __restrict__ dinv,
                                                      int* __restrict__ off,
                                                      int* __restrict__ csr) {
    int g = blockIdx.x, t = threadIdx.x;
    __shared__ int cnt[NPG];               // counts, then cursors
    __shared__ int soff[NPG];              // local start offsets
    __shared__ unsigned short lcsr[EPG];   // src local ids, dst-grouped
    __shared__ int red[1024];
    const int gbase = g * NPG;
    const int ebase = g * EPG;
    const int* __restrict__ srcp = ei + ebase;
    const int* __restrict__ dstp = ei + E + ebase;

    for (int i = t; i < NPG; i += 1024) cnt[i] = 0;
    __syncthreads();
    // phase 1: count in-degree (LDS atomics)
    for (int i = t; i < EPG; i += 1024) atomicAdd(&cnt[dstp[i] - gbase], 1);
    __syncthreads();
    // phase 2: exclusive scan over 1000 counts (1/thread, Hillis-Steele on 1024)
    int v = (t < NPG) ? cnt[t] : 0;
    red[t] = v;
    __syncthreads();
    for (int o = 1; o < 1024; o <<= 1) {
        int xx = (t >= o) ? red[t - o] : 0;
        __syncthreads();
        red[t] += xx;
        __syncthreads();
    }
    if (t < NPG) soff[t] = red[t] - v;     // exclusive prefix
    __syncthreads();
    // outputs: deg, dinv, off (coalesced)
    for (int i = t; i < NPG; i += 1024) {
        int d = cnt[i];
        deg[gbase + i] = d;
        dinv[gbase + i] = 1.0f / sqrtf((float)(d + 1));
        off[gbase + i] = ebase + soff[i];
    }
    __syncthreads();
    // reset cursors
    for (int i = t; i < NPG; i += 1024) cnt[i] = soff[i];
    __syncthreads();
    // phase 3: scatter src into dst-grouped order (LDS cursor atomics + LDS writes)
    for (int i = t; i < EPG; i += 1024) {
        int d = dstp[i] - gbase;
        int pos = atomicAdd(&cnt[d], 1);
        lcsr[pos] = (unsigned short)(srcp[i] - gbase);
    }
    __syncthreads();
    // phase 4: dump csr as coalesced int4 stores (EPG % 4 == 0)
    int4* co = (int4*)(csr + ebase);
    for (int i = t; i < EPG / 4; i += 1024) {
        int4 vv;
        vv.x = gbase + (int)lcsr[i * 4 + 0];
        vv.y = gbase + (int)lcsr[i * 4 + 1];
        vv.z = gbase + (int)lcsr[i * 4 + 2];
        vv.w = gbase + (int)lcsr[i * 4 + 3];
        co[i] = vv;
    }
}

// ---------------- h2 = (x @ W) * dinv[row] : register-tiled, 2 rows/thread, W in LDS --------
__global__ __launch_bounds__(256) void gemm_k(const float* __restrict__ x,
                                              const float* __restrict__ W,
                                              const float* __restrict__ dinv,
                                              float* __restrict__ h2, int N) {
    __shared__ float sW[C * C];
    int t = threadIdx.x;
    for (int i = t; i < C * C / 4; i += 256) ((float4*)sW)[i] = ((const float4*)W)[i];
    __syncthreads();
    int r0 = blockIdx.x * 512 + t;
    int r1 = r0 + 256;
    if (r0 >= N) return;
    bool has1 = (r1 < N);
    const float4* x0 = (const float4*)(x + (size_t)r0 * C);
    const float4* x1 = (const float4*)(x + (size_t)(has1 ? r1 : r0) * C);
    float acc0[C], acc1[C];
#pragma unroll
    for (int i = 0; i < C; ++i) { acc0[i] = 0.f; acc1[i] = 0.f; }
    float4 a0 = x0[0], a1 = x1[0];
    for (int k4 = 0; k4 < 16; ++k4) {
        float4 b0, b1;
        if (k4 < 15) { b0 = x0[k4 + 1]; b1 = x1[k4 + 1]; }
        const float4* wr = (const float4*)(sW + k4 * 4 * C);
        const float* a0f = (const float*)&a0;
        const float* a1f = (const float*)&a1;
#pragma unroll
        for (int c4 = 0; c4 < 16; ++c4) {
            float4 w[4];
            w[0] = wr[c4]; w[1] = wr[16 + c4]; w[2] = wr[32 + c4]; w[3] = wr[48 + c4];
            const float* wf = (const float*)w;
#pragma unroll
            for (int j = 0; j < 4; ++j) {
                float s0 = acc0[c4 * 4 + j], s1 = acc1[c4 * 4 + j];
#pragma unroll
                for (int kk = 0; kk < 4; ++kk) {
                    float wv = wf[kk * 4 + j];
                    s0 = fmaf(a0f[kk], wv, s0);
                    s1 = fmaf(a1f[kk], wv, s1);
                }
                acc0[c4 * 4 + j] = s0; acc1[c4 * 4 + j] = s1;
            }
        }
        a0 = b0; a1 = b1;
    }
    float dv0 = dinv[r0];
    float dv1 = has1 ? dinv[r1] : 0.f;
#pragma unroll
    for (int i = 0; i < C; ++i) { acc0[i] *= dv0; acc1[i] *= dv1; }
    float4* h0 = (float4*)(h2 + (size_t)r0 * C);
#pragma unroll
    for (int q = 0; q < 16; ++q) h0[q] = ((float4*)acc0)[q];
    if (has1) {
        float4* h1 = (float4*)(h2 + (size_t)r1 * C);
#pragma unroll
        for (int q = 0; q < 16; ++q) h1[q] = ((float4*)acc1)[q];
    }
}

// ---------------- gather aggregation: 4 nodes per wave, lane = channel -----------------
// 4 independent gather chains per wave. Each node's chunk loop is guarded by its OWN
// rounded trip count (wave-uniform condition -> s_cbranch, near-free when skipped),
// so padding waste is <=3 edges/node instead of max-of-4 (~8). Pad slots hold the
// node's own id; compensated via coef = 1 - padcount folded into the self-term fma.
// Per-graph centroid partial sums fused in: LDS accumulate + 1 global atomic per block.
__global__ __launch_bounds__(256) void gather_k(const int* __restrict__ csr,
                                                const int* __restrict__ off,
                                                const int* __restrict__ deg,
                                                const float* __restrict__ h2,
                                                const float* __restrict__ dinv,
                                                const float* __restrict__ bias,
                                                float* __restrict__ out2,
                                                float* __restrict__ cen_sum,
                                                int N, int B) {
    __shared__ float cenacc[C];
    int blk = blockIdx.x;
    int wave = threadIdx.x >> 6;
    int lane = threadIdx.x & 63;
    int t = threadIdx.x;
    int g, blkin;
    if ((B & 7) == 0) {                    // XCD swizzle: whole graph on one XCD
        int xcd = blk & 7, slot = blk >> 3;
        g = (slot / BPG) * 8 + xcd;
        blkin = slot % BPG;
    } else {
        g = blk / BPG;
        blkin = blk % BPG;
    }
    if (t < C) cenacc[t] = 0.f;
    __syncthreads();

    int base = blkin * 4 + wave;
    bool active = (base < NPG / 4);
    if (active) {
        int nA = g * NPG + base;
        int nB = nA + 250, nC = nA + 500, nD = nA + 750;
        int oA = off[nA], oB = off[nB], oC = off[nC], oD = off[nD];
        int dA = deg[nA], dB = deg[nB], dC = deg[nC], dD = deg[nD];
        float diA = dinv[nA], diB = dinv[nB], diC = dinv[nC], diD = dinv[nD];
        float hA = h2[(size_t)nA * C + lane];
        float hB = h2[(size_t)nB * C + lane];
        float hC = h2[(size_t)nC * C + lane];
        float hD = h2[(size_t)nD * C + lane];
        float bv = bias[lane];
        // neighbor id vectors, padded with own node id
        int svA = (lane < dA) ? csr[oA + lane] : nA;
        int svB = (lane < dB) ? csr[oB + lane] : nB;
        int svC = (lane < dC) ? csr[oC + lane] : nC;
        int svD = (lane < dD) ? csr[oD + lane] : nD;
        int jmA = dA < 64 ? dA : 64;
        int jmB = dB < 64 ? dB : 64;
        int jmC = dC < 64 ? dC : 64;
        int jmD = dD < 64 ? dD : 64;
        int rA = (jmA + 3) & ~3, rB = (jmB + 3) & ~3;
        int rC = (jmC + 3) & ~3, rD = (jmD + 3) & ~3;
        int m0 = rA > rB ? rA : rB;
        int m1 = rC > rD ? rC : rD;
        int mmax = m0 > m1 ? m0 : m1;
        float aA = 0.f, aB = 0.f, aC = 0.f, aD = 0.f;
        for (int j = 0; j < mmax; j += 4) {
            if (j < rA) {
                int s0 = readlane_i(svA, j + 0), s1 = readlane_i(svA, j + 1);
                int s2 = readlane_i(svA, j + 2), s3 = readlane_i(svA, j + 3);
                float v0 = h2[(size_t)s0 * C + lane];
                float v1 = h2[(size_t)s1 * C + lane];
                float v2 = h2[(size_t)s2 * C + lane];
                float v3 = h2[(size_t)s3 * C + lane];
                aA += (v0 + v1) + (v2 + v3);
            }
            if (j < rB) {
                int s0 = readlane_i(svB, j + 0), s1 = readlane_i(svB, j + 1);
                int s2 = readlane_i(svB, j + 2), s3 = readlane_i(svB, j + 3);
                float v0 = h2[(size_t)s0 * C + lane];
                float v1 = h2[(size_t)s1 * C + lane];
                float v2 = h2[(size_t)s2 * C + lane];
                float v3 = h2[(size_t)s3 * C + lane];
                aB += (v0 + v1) + (v2 + v3);
            }
            if (j < rC) {
                int s0 = readlane_i(svC, j + 0), s1 = readlane_i(svC, j + 1);
                int s2 = readlane_i(svC, j + 2), s3 = readlane_i(svC, j + 3);
                float v0 = h2[(size_t)s0 * C + lane];
                float v1 = h2[(size_t)s1 * C + lane];
                float v2 = h2[(size_t)s2 * C + lane];
                float v3 = h2[(size_t)s3 * C + lane];
                aC += (v0 + v1) + (v2 + v3);
            }
            if (j < rD) {
                int s0 = readlane_i(svD, j + 0), s1 = readlane_i(svD, j + 1);
                int s2 = readlane_i(svD, j + 2), s3 = readlane_i(svD, j + 3);
                float v0 = h2[(size_t)s0 * C + lane];
                float v1 = h2[(size_t)s1 * C + lane];
                float v2 = h2[(size_t)s2 * C + lane];
                float v3 = h2[(size_t)s3 * C + lane];
                aD += (v0 + v1) + (v2 + v3);
            }
        }
        // deg > 64 fallback (essentially never: Poisson(16))
        for (int j = 64; j < dA; ++j) aA += h2[(size_t)csr[oA + j] * C + lane];
        for (int j = 64; j < dB; ++j) aB += h2[(size_t)csr[oB + j] * C + lane];
        for (int j = 64; j < dC; ++j) aC += h2[(size_t)csr[oC + j] * C + lane];
        for (int j = 64; j < dD; ++j) aD += h2[(size_t)csr[oD + j] * C + lane];
        // pad compensation: acc holds (rN - jmN) extra copies of own row; want exactly +1
        float cA = 1.0f - (float)(rA - jmA);
        float cB = 1.0f - (float)(rB - jmB);
        float cC = 1.0f - (float)(rC - jmC);
        float cD = 1.0f - (float)(rD - jmD);
        float resA = fmaf(diA, fmaf(cA, hA, aA), bv);
        float resB = fmaf(diB, fmaf(cB, hB, aB), bv);
        float resC = fmaf(diC, fmaf(cC, hC, aC), bv);
        float resD = fmaf(diD, fmaf(cD, hD, aD), bv);
        out2[(size_t)nA * C + lane] = resA;
        out2[(size_t)nB * C + lane] = resB;
        out2[(size_t)nC * C + lane] = resC;
        out2[(size_t)nD * C + lane] = resD;
        float csum = (resA + resB) + (resC + resD);
        atomicAdd(&cenacc[lane], csum);
    }
    __syncthreads();
    if (t < C) atomicAdd(&cen_sum[(size_t)g * C + t], cenacc[t]);
}

// ---------------- fused per-graph tail: centroid-finalize + score + softmax-KL +
//                  bitonic argsort + top-K + edge re-index, all in one block/graph --------
__global__ __launch_bounds__(1024) void post_k(const float* __restrict__ out2,
                                               const float* __restrict__ cen_sum,
                                               const int* __restrict__ ei,
                                               const float* __restrict__ eattr,
                                               float* __restrict__ o_xnew,
                                               float* __restrict__ o_newei,
                                               float* __restrict__ o_eattr,
                                               float* __restrict__ o_mask,
                                               float* __restrict__ o_batch,
                                               float* __restrict__ o_perm,
                                               float* __restrict__ o_kl,
                                               float* __restrict__ o_ind,
                                               int E) {
    __shared__ float ss[NPG];                  // scores (LDS-resident for whole tail)
    __shared__ float red[1024];
    __shared__ unsigned long long kk[1024];
    __shared__ int   map[NPG];                 // node -> new index, graph-local
    __shared__ float cenl[C];
    __shared__ float cns;
    int g = blockIdx.x, t = threadIdx.x;
    int wave = t >> 6, lane = t & 63;
    const int gbase = g * NPG;
    const int ebase = g * EPG;

    // centroid finalize
    if (t < C) cenl[t] = cen_sum[(size_t)g * C + t] * (1.0f / 1000.0f);
    __syncthreads();
    if (t < 64) {
        float m = cenl[t];
        float v = m * m;
        for (int o = 32; o > 0; o >>= 1) v += __shfl_down(v, o, 64);
        if (t == 0) cns = sqrtf(v);
    }
    __syncthreads();
    // score: wave per node, lane = channel, shfl-reduce dot + sqnorm
    float cv = cenl[lane];
    float cn = cns;
    for (int n = wave; n < NPG; n += 16) {
        float a = out2[(size_t)(gbase + n) * C + lane];
        float num = a * cv;
        float sq = a * a;
        for (int o = 32; o > 0; o >>= 1) {
            num += __shfl_down(num, o, 64);
            sq  += __shfl_down(sq, o, 64);
        }
        if (lane == 0) ss[n] = num / (sqrtf(sq) * cn + 1e-8f);
    }
    __syncthreads();
    // softmax KL vs uniform
    float mx = -INFINITY;
    for (int i = t; i < NPG; i += 1024) mx = fmaxf(mx, ss[i]);
    red[t] = mx;
    __syncthreads();
    for (int w = 512; w > 0; w >>= 1) { if (t < w) red[t] = fmaxf(red[t], red[t + w]); __syncthreads(); }
    mx = red[0];
    __syncthreads();
    float se = 0.f;
    for (int i = t; i < NPG; i += 1024) se += expf(ss[i] - mx);
    red[t] = se;
    __syncthreads();
    for (int w = 512; w > 0; w >>= 1) { if (t < w) red[t] += red[t + w]; __syncthreads(); }
    float lse = logf(red[0]);
    __syncthreads();
    float kl = 0.f;
    const float ln_npg = 6.9077552790f;
    for (int i = t; i < NPG; i += 1024) {
        float lp = ss[i] - mx - lse;
        kl += expf(lp) * (lp + ln_npg);
    }
    red[t] = kl;
    __syncthreads();
    for (int w = 512; w > 0; w >>= 1) { if (t < w) red[t] += red[t + w]; __syncthreads(); }
    if (t == 0) o_kl[g] = red[0];
    // sort keys: descending stable argsort via ascending (~flipped_score, idx)
    unsigned long long v;
    if (t < NPG) {
        unsigned u = __float_as_uint(ss[t]);
        u = (u & 0x80000000u) ? ~u : (u | 0x80000000u);
        v = ((unsigned long long)(~u) << 32) | (unsigned)t;
    } else {
        v = ~0ULL;
    }
    __syncthreads();
    kk[t] = v;
    __syncthreads();
    for (int k = 2; k <= 1024; k <<= 1) {
        for (int j = k >> 1; j > 0; j >>= 1) {
            int ixj = t ^ j;
            if (ixj > t) {
                unsigned long long a = kk[t], b2 = kk[ixj];
                bool up = ((t & k) == 0);
                if ((a > b2) == up) { kk[t] = b2; kk[ixj] = a; }
            }
            __syncthreads();
        }
    }
    // indices output + mapping init
    if (t < NPG) {
        int idx = (int)(kk[t] & 0xFFFFFFFFULL);
        o_ind[(size_t)g * NPG + t] = (float)idx;
        map[t] = -1;
    }
    __syncthreads();
    // top-K bookkeeping
    if (t < KTOP) {
        int node = (int)(kk[t] & 0xFFFFFFFFULL);
        map[node] = g * KTOP + t;
        o_perm[(size_t)g * KTOP + t] = (float)(gbase + node);
        o_batch[(size_t)g * KTOP + t] = (float)g;
    }
    __syncthreads();
    // x_new rows: wave per row (coalesced 256B read+write)
    for (int r = wave; r < KTOP; r += 16) {
        int node = (int)(kk[r] & 0xFFFFFFFFULL);
        float tn = tanhf(ss[node]);
        o_xnew[((size_t)g * KTOP + r) * C + lane] =
            out2[(size_t)(gbase + node) * C + lane] * tn;
    }
    // edge re-index + mask + attr via LDS map (x4 vectorized; EPG % 4 == 0)
    const int4* src4 = (const int4*)(ei + ebase);
    const int4* dst4 = (const int4*)(ei + E + ebase);
    const float4* at4 = (const float4*)(eattr + ebase);
    float4* nei0 = (float4*)(o_newei + ebase);
    float4* nei1 = (float4*)(o_newei + E + ebase);
    float4* msk4 = (float4*)(o_mask + ebase);
    float4* eat4 = (float4*)(o_eattr + ebase);
    for (int e4 = t; e4 < EPG / 4; e4 += 1024) {
        int4 s = src4[e4], d = dst4[e4];
        int a0 = map[s.x - gbase], a1 = map[s.y - gbase];
        int a2 = map[s.z - gbase], a3 = map[s.w - gbase];
        int b0 = map[d.x - gbase], b1 = map[d.y - gbase];
        int b2 = map[d.z - gbase], b3 = map[d.w - gbase];
        float4 f0 = { (float)a0, (float)a1, (float)a2, (float)a3 };
        float4 f1 = { (float)b0, (float)b1, (float)b2, (float)b3 };
        nei0[e4] = f0;
        nei1[e4] = f1;
        float4 at = at4[e4];
        float4 mk, ea;
        mk.x = (a0 >= 0 && b0 >= 0) ? 1.0f : 0.0f;
        mk.y = (a1 >= 0 && b1 >= 0) ? 1.0f : 0.0f;
        mk.z = (a2 >= 0 && b2 >= 0) ? 1.0f : 0.0f;
        mk.w = (a3 >= 0 && b3 >= 0) ? 1.0f : 0.0f;
        ea.x = mk.x != 0.0f ? at.x : 0.0f;
        ea.y = mk.y != 0.0f ? at.y : 0.0f;
        ea.z = mk.z != 0.0f ? at.z : 0.0f;
        ea.w = mk.w != 0.0f ? at.w : 0.0f;
        msk4[e4] = mk;
        eat4[e4] = ea;
    }
}

extern "C" void kernel_launch(void* const* d_in, const int* in_sizes, int n_in,
                              void* d_out, int out_size, void* d_ws, size_t ws_size,
                              hipStream_t stream) {
    (void)n_in; (void)out_size; (void)ws_size;
    const float* x     = (const float*)d_in[1];
    const int*   ei    = (const int*)d_in[2];
    const float* eattr = (const float*)d_in[3];
    const float* W     = (const float*)d_in[5];
    const float* bias  = (const float*)d_in[6];

    const int N  = in_sizes[1] / C;    // 256000
    const int E  = in_sizes[2] / 2;    // 4096000
    const int B  = N / NPG;            // 256
    const int BK = B * KTOP;           // 128000

    // workspace layout
    char* wsp = (char*)d_ws;
    float* out2    = (float*)wsp; wsp += (size_t)N * C * 4;   // 65.5 MB
    float* dinv    = (float*)wsp; wsp += (size_t)N * 4;
    int*   deg     = (int*)wsp;   wsp += (size_t)N * 4;
    int*   off     = (int*)wsp;   wsp += (size_t)N * 4;
    float* cen_sum = (float*)wsp; wsp += (size_t)B * C * 4;

    // output layout (flat f32, reference return order)
    float* out     = (float*)d_out;
    float* o_xnew  = out;                                   // BK*C
    float* o_newei = o_xnew + (size_t)BK * C;               // 2E
    float* o_eattr = o_newei + 2 * (size_t)E;               // E
    float* o_mask  = o_eattr + (size_t)E;                   // E
    float* o_batch = o_mask + (size_t)E;                    // BK
    float* o_perm  = o_batch + (size_t)BK;                  // BK
    float* o_kl    = o_perm + (size_t)BK;                   // B
    float* o_ind   = o_kl + (size_t)B;                      // B*NPG

    // scratch aliased onto d_out (dead before those outputs are written)
    float* h2buf = out;                // N*C floats (= o_xnew + o_newei region)
    int*   csr   = (int*)o_eattr;      // E ints

    hipMemsetAsync(cen_sum, 0, (size_t)B * C * 4, stream);

    build_graph_k<<<B, 1024, 0, stream>>>(ei, E, deg, dinv, off, csr);
    gemm_k<<<(N + 511) / 512, 256, 0, stream>>>(x, W, dinv, h2buf, N);
    gather_k<<<B * BPG, 256, 0, stream>>>(csr, off, deg, h2buf, dinv, bias, out2,
                                          cen_sum, N, B);
    post_k<<<B, 1024, 0, stream>>>(out2, cen_sum, ei, eattr,
                                   o_xnew, o_newei, o_eattr, o_mask,
                                   o_batch, o_perm, o_kl, o_ind, E);
}